// Round 2
// baseline (320.780 us; speedup 1.0000x reference)
//
#include <hip/hip_runtime.h>

typedef __bf16 bf16;
typedef __attribute__((ext_vector_type(8))) __bf16 bf16x8;
typedef __attribute__((ext_vector_type(4))) float f32x4;

#define LOG2E 1.44269504088896340736f

// ---------------- Kernel A: fp32 -> bf16 cast (grid-stride, 8 elems/thread) ----------------
__global__ __launch_bounds__(256) void cast_k(const float* __restrict__ in,
                                              bf16* __restrict__ out, int n) {
    int idx = (blockIdx.x * 256 + threadIdx.x) * 8;
    if (idx + 8 <= n) {
        float4 a = *(const float4*)(in + idx);
        float4 b = *(const float4*)(in + idx + 4);
        bf16 v[8] = {(bf16)a.x, (bf16)a.y, (bf16)a.z, (bf16)a.w,
                     (bf16)b.x, (bf16)b.y, (bf16)b.z, (bf16)b.w};
        *(uint4*)(out + idx) = *(const uint4*)v;
    }
}

// ---------------- Kernel 0: tiled transpose + cast  out[C][R] = (bf16)in[R][C] ----------------
__global__ __launch_bounds__(256) void transpose_cast_k(const float* __restrict__ in,
                                                        bf16* __restrict__ out,
                                                        int R, int C) {
    __shared__ float t[32][33];
    int tx = threadIdx.x & 31, ty = threadIdx.x >> 5;  // 32 x 8
    int rbase = blockIdx.y * 32, cbase = blockIdx.x * 32;
#pragma unroll
    for (int i = 0; i < 4; i++) {
        int r = ty + i * 8;
        t[r][tx] = in[(size_t)(rbase + r) * C + cbase + tx];
    }
    __syncthreads();
#pragma unroll
    for (int i = 0; i < 4; i++) {
        int r = ty + i * 8;
        out[(size_t)(cbase + r) * R + rbase + tx] = (bf16)t[tx][r];
    }
}

// ---------------- Kernel 1: fused QKV GEMM + bias + RoPE ----------------
// Xb [4096][1024] bf16, WT layouts [N][D] bf16. Out: Q [B][H][S][64], K/V [B][KV][S][64].
__global__ __launch_bounds__(256) void qkv_gemm(const bf16* __restrict__ X,
                                                const bf16* __restrict__ WqT,
                                                const bf16* __restrict__ WkT,
                                                const bf16* __restrict__ WvT,
                                                const float* __restrict__ bq,
                                                const float* __restrict__ bk,
                                                const float* __restrict__ bv,
                                                bf16* __restrict__ Qb,
                                                bf16* __restrict__ Kb,
                                                bf16* __restrict__ Vb) {
    int tt = blockIdx.x;   // token tile (64 tokens)
    int gy = blockIdx.y;   // 0..23: 0-15 Q heads, 16-19 K kv-heads, 20-23 V kv-heads
    const bf16* WT;
    const float* bias;
    bf16* dst;
    int mode, head;
    if (gy < 16)      { head = gy;      WT = WqT + (size_t)head * 64 * 1024; bias = bq + head * 64; dst = Qb; mode = 0; }
    else if (gy < 20) { head = gy - 16; WT = WkT + (size_t)head * 64 * 1024; bias = bk + head * 64; dst = Kb; mode = 1; }
    else              { head = gy - 20; WT = WvT + (size_t)head * 64 * 1024; bias = bv + head * 64; dst = Vb; mode = 2; }

    __shared__ unsigned short Xs[64 * 72];
    __shared__ unsigned short Ws[64 * 72];
    int tid = threadIdx.x;
    int w = tid >> 6, lane = tid & 63, l15 = lane & 15, quad = lane >> 4;

    f32x4 acc[4] = {};
    for (int k0 = 0; k0 < 1024; k0 += 64) {
#pragma unroll
        for (int i = tid; i < 512; i += 256) {
            int row = i >> 3, ch = i & 7;
            uint4 xv = *(const uint4*)(X + (size_t)(tt * 64 + row) * 1024 + k0 + ch * 8);
            *(uint4*)&Xs[row * 72 + ch * 8] = xv;
            uint4 wv = *(const uint4*)(WT + (size_t)row * 1024 + k0 + ch * 8);
            *(uint4*)&Ws[row * 72 + ch * 8] = wv;
        }
        __syncthreads();
        bf16x8 a0 = *(const bf16x8*)&Xs[(w * 16 + l15) * 72 + quad * 8];
        bf16x8 a1 = *(const bf16x8*)&Xs[(w * 16 + l15) * 72 + 32 + quad * 8];
#pragma unroll
        for (int c = 0; c < 4; c++) {
            bf16x8 b0 = *(const bf16x8*)&Ws[(c * 16 + l15) * 72 + quad * 8];
            bf16x8 b1 = *(const bf16x8*)&Ws[(c * 16 + l15) * 72 + 32 + quad * 8];
            acc[c] = __builtin_amdgcn_mfma_f32_16x16x32_bf16(a0, b0, acc[c], 0, 0, 0);
            acc[c] = __builtin_amdgcn_mfma_f32_16x16x32_bf16(a1, b1, acc[c], 0, 0, 0);
        }
        __syncthreads();
    }

#pragma unroll
    for (int r = 0; r < 4; r++) {
        int token = tt * 64 + w * 16 + quad * 4 + r;
        int b = token >> 11, s = token & 2047;
        float vals[4];
#pragma unroll
        for (int c = 0; c < 4; c++) vals[c] = acc[c][r] + bias[c * 16 + l15];
        if (mode <= 1) {  // RoPE for Q,K
#pragma unroll
            for (int c = 0; c < 2; c++) {
                int i = c * 16 + l15;  // 0..31
                float inv = exp2f(-0.41524100370589830f * (float)i);  // 10000^(-i/32)
                float ang = (float)s * inv;
                float sn, cs;
                __sincosf(ang, &sn, &cs);
                // use accurate version to match numpy:
                sn = sinf(ang); cs = cosf(ang);
                float x1 = vals[c], x2 = vals[c + 2];
                vals[c]     = x1 * cs - x2 * sn;
                vals[c + 2] = x1 * sn + x2 * cs;
            }
        }
        size_t base;
        if (mode == 0) base = (((size_t)b * 16 + head) * 2048 + s) * 64;
        else           base = (((size_t)b * 4  + head) * 2048 + s) * 64;
#pragma unroll
        for (int c = 0; c < 4; c++) dst[base + c * 16 + l15] = (bf16)vals[c];
    }
}

// ---------------- Kernel 2: flash attention ----------------
// grid (32 qtiles, 16 heads, 2 batch), block 256 = 4 waves x 16 q-rows
__global__ __launch_bounds__(256) void attn_k(const bf16* __restrict__ Qb,
                                              const bf16* __restrict__ Kb,
                                              const bf16* __restrict__ Vb,
                                              const float* __restrict__ mask,
                                              bf16* __restrict__ Ob) {
    int qt = blockIdx.x, h = blockIdx.y, b = blockIdx.z;
    int kvh = h >> 2;  // rep = 4

    __shared__ unsigned short Ks[64 * 72];   // [key][d]
    __shared__ unsigned short Vs[64 * 72];   // [d][key]  (transposed)
    __shared__ unsigned short Ps[4][16 * 72]; // per-wave P tile [q][key]
    __shared__ float Ms[64];                  // per-key bias (log2 domain)

    int tid = threadIdx.x, w = tid >> 6, lane = tid & 63, l15 = lane & 15, quad = lane >> 4;

    size_t qbase = (((size_t)b * 16 + h) * 2048 + (size_t)qt * 64 + w * 16 + l15) * 64;
    bf16x8 qa0 = *(const bf16x8*)(Qb + qbase + quad * 8);
    bf16x8 qa1 = *(const bf16x8*)(Qb + qbase + 32 + quad * 8);

    f32x4 oacc[4] = {};
    float m2[4] = {-1e30f, -1e30f, -1e30f, -1e30f};
    float lsum[4] = {0.f, 0.f, 0.f, 0.f};
    const float SCALE = 0.125f * LOG2E;  // 1/sqrt(64) folded with log2(e)

    for (int kt = 0; kt < 32; kt++) {
        size_t kbase = (((size_t)b * 4 + kvh) * 2048 + (size_t)kt * 64) * 64;
#pragma unroll
        for (int i = tid; i < 512; i += 256) {
            int row = i >> 3, ch = i & 7;
            uint4 kv4 = *(const uint4*)(Kb + kbase + row * 64 + ch * 8);
            *(uint4*)&Ks[row * 72 + ch * 8] = kv4;
            uint4 vv4 = *(const uint4*)(Vb + kbase + row * 64 + ch * 8);
            unsigned int u[4] = {vv4.x, vv4.y, vv4.z, vv4.w};
#pragma unroll
            for (int j = 0; j < 4; j++) {
                Vs[(ch * 8 + 2 * j) * 72 + row]     = (unsigned short)(u[j] & 0xffffu);
                Vs[(ch * 8 + 2 * j + 1) * 72 + row] = (unsigned short)(u[j] >> 16);
            }
        }
        if (tid < 64) {
            float mv = mask[(size_t)b * 2048 + kt * 64 + tid];
            Ms[tid] = (1.0f - mv) * (-1e9f) * LOG2E;
        }
        __syncthreads();

        // ---- S = Q K^T (scores in log2 domain) ----
        f32x4 sc[4] = {};
#pragma unroll
        for (int c = 0; c < 4; c++) {
            bf16x8 kb0 = *(const bf16x8*)&Ks[(c * 16 + l15) * 72 + quad * 8];
            bf16x8 kb1 = *(const bf16x8*)&Ks[(c * 16 + l15) * 72 + 32 + quad * 8];
            sc[c] = __builtin_amdgcn_mfma_f32_16x16x32_bf16(qa0, kb0, sc[c], 0, 0, 0);
            sc[c] = __builtin_amdgcn_mfma_f32_16x16x32_bf16(qa1, kb1, sc[c], 0, 0, 0);
        }
        float biasc[4];
#pragma unroll
        for (int c = 0; c < 4; c++) biasc[c] = Ms[c * 16 + l15];
#pragma unroll
        for (int c = 0; c < 4; c++)
#pragma unroll
            for (int r = 0; r < 4; r++) sc[c][r] = sc[c][r] * SCALE + biasc[c];

        // ---- online softmax ----
        float mx[4], rs[4], alpha[4];
#pragma unroll
        for (int r = 0; r < 4; r++)
            mx[r] = fmaxf(fmaxf(sc[0][r], sc[1][r]), fmaxf(sc[2][r], sc[3][r]));
#pragma unroll
        for (int off = 1; off < 16; off <<= 1)
#pragma unroll
            for (int r = 0; r < 4; r++) mx[r] = fmaxf(mx[r], __shfl_xor(mx[r], off, 64));
#pragma unroll
        for (int r = 0; r < 4; r++) {
            float mn = fmaxf(m2[r], mx[r]);
            alpha[r] = exp2f(m2[r] - mn);
            m2[r] = mn;
        }
#pragma unroll
        for (int c = 0; c < 4; c++)
#pragma unroll
            for (int r = 0; r < 4; r++) sc[c][r] = exp2f(sc[c][r] - m2[r]);
#pragma unroll
        for (int r = 0; r < 4; r++) rs[r] = (sc[0][r] + sc[1][r]) + (sc[2][r] + sc[3][r]);
#pragma unroll
        for (int off = 1; off < 16; off <<= 1)
#pragma unroll
            for (int r = 0; r < 4; r++) rs[r] += __shfl_xor(rs[r], off, 64);
#pragma unroll
        for (int r = 0; r < 4; r++) lsum[r] = lsum[r] * alpha[r] + rs[r];
#pragma unroll
        for (int c = 0; c < 4; c++)
#pragma unroll
            for (int r = 0; r < 4; r++) oacc[c][r] *= alpha[r];

        // ---- P: C-layout -> bf16 A-layout via LDS ----
        bf16* pw = (bf16*)Ps[w];
#pragma unroll
        for (int c = 0; c < 4; c++)
#pragma unroll
            for (int r = 0; r < 4; r++)
                pw[(quad * 4 + r) * 72 + c * 16 + l15] = (bf16)sc[c][r];
        __syncthreads();  // also guarantees P visibility + all waves done with Ks

        bf16x8 pa0 = *(const bf16x8*)&Ps[w][l15 * 72 + quad * 8];
        bf16x8 pa1 = *(const bf16x8*)&Ps[w][l15 * 72 + 32 + quad * 8];
#pragma unroll
        for (int c = 0; c < 4; c++) {
            bf16x8 vb0 = *(const bf16x8*)&Vs[(c * 16 + l15) * 72 + quad * 8];
            bf16x8 vb1 = *(const bf16x8*)&Vs[(c * 16 + l15) * 72 + 32 + quad * 8];
            oacc[c] = __builtin_amdgcn_mfma_f32_16x16x32_bf16(pa0, vb0, oacc[c], 0, 0, 0);
            oacc[c] = __builtin_amdgcn_mfma_f32_16x16x32_bf16(pa1, vb1, oacc[c], 0, 0, 0);
        }
        __syncthreads();  // Vs reads done before next stage overwrites
    }

    // epilogue: O[b][q][h*64+d] = oacc / l
#pragma unroll
    for (int r = 0; r < 4; r++) {
        float rcp = 1.0f / lsum[r];
        int q = qt * 64 + w * 16 + quad * 4 + r;
        size_t base = ((size_t)b * 2048 + q) * 1024 + h * 64;
#pragma unroll
        for (int c = 0; c < 4; c++) Ob[base + c * 16 + l15] = (bf16)(oacc[c][r] * rcp);
    }
}

// ---------------- Kernel 3: O projection (fp32 output) ----------------
__global__ __launch_bounds__(256) void oproj_gemm(const bf16* __restrict__ A,
                                                  const bf16* __restrict__ WoT,
                                                  const float* __restrict__ bo,
                                                  float* __restrict__ out) {
    int tt = blockIdx.x, gy = blockIdx.y;  // gy 0..15
    const bf16* WT = WoT + (size_t)gy * 64 * 1024;

    __shared__ unsigned short Xs[64 * 72];
    __shared__ unsigned short Ws[64 * 72];
    int tid = threadIdx.x;
    int w = tid >> 6, lane = tid & 63, l15 = lane & 15, quad = lane >> 4;

    f32x4 acc[4] = {};
    for (int k0 = 0; k0 < 1024; k0 += 64) {
#pragma unroll
        for (int i = tid; i < 512; i += 256) {
            int row = i >> 3, ch = i & 7;
            uint4 xv = *(const uint4*)(A + (size_t)(tt * 64 + row) * 1024 + k0 + ch * 8);
            *(uint4*)&Xs[row * 72 + ch * 8] = xv;
            uint4 wv = *(const uint4*)(WT + (size_t)row * 1024 + k0 + ch * 8);
            *(uint4*)&Ws[row * 72 + ch * 8] = wv;
        }
        __syncthreads();
        bf16x8 a0 = *(const bf16x8*)&Xs[(w * 16 + l15) * 72 + quad * 8];
        bf16x8 a1 = *(const bf16x8*)&Xs[(w * 16 + l15) * 72 + 32 + quad * 8];
#pragma unroll
        for (int c = 0; c < 4; c++) {
            bf16x8 b0 = *(const bf16x8*)&Ws[(c * 16 + l15) * 72 + quad * 8];
            bf16x8 b1 = *(const bf16x8*)&Ws[(c * 16 + l15) * 72 + 32 + quad * 8];
            acc[c] = __builtin_amdgcn_mfma_f32_16x16x32_bf16(a0, b0, acc[c], 0, 0, 0);
            acc[c] = __builtin_amdgcn_mfma_f32_16x16x32_bf16(a1, b1, acc[c], 0, 0, 0);
        }
        __syncthreads();
    }
#pragma unroll
    for (int r = 0; r < 4; r++) {
        int token = tt * 64 + w * 16 + quad * 4 + r;
#pragma unroll
        for (int c = 0; c < 4; c++) {
            int n = gy * 64 + c * 16 + l15;
            out[(size_t)token * 1024 + n] = acc[c][r] + bo[n];
        }
    }
}

// ---------------- launch ----------------
extern "C" void kernel_launch(void* const* d_in, const int* in_sizes, int n_in,
                              void* d_out, int out_size, void* d_ws, size_t ws_size,
                              hipStream_t stream) {
    const float* X    = (const float*)d_in[0];
    const float* mask = (const float*)d_in[1];
    const float* Wq   = (const float*)d_in[2];
    const float* bq   = (const float*)d_in[3];
    const float* Wk   = (const float*)d_in[4];
    const float* bk   = (const float*)d_in[5];
    const float* Wv   = (const float*)d_in[6];
    const float* bv   = (const float*)d_in[7];
    const float* Wo   = (const float*)d_in[8];
    const float* bo   = (const float*)d_in[9];
    float* out = (float*)d_out;
    bf16* ws  = (bf16*)d_ws;

    // workspace layout (bf16 elements)
    bf16* Xb  = ws;                       // 4096x1024
    bf16* WqT = Xb + (size_t)4096 * 1024; // 1024x1024
    bf16* WkT = WqT + 1024 * 1024;        // 256x1024
    bf16* WvT = WkT + 256 * 1024;         // 256x1024
    bf16* WoT = WvT + 256 * 1024;         // 1024x1024
    bf16* Qb  = WoT + 1024 * 1024;        // [2][16][2048][64]
    bf16* Kb  = Qb + (size_t)2 * 16 * 2048 * 64;  // [2][4][2048][64]
    bf16* Vb  = Kb + (size_t)2 * 4 * 2048 * 64;
    bf16* Ab  = Vb + (size_t)2 * 4 * 2048 * 64;   // [2][2048][1024]

    cast_k<<<2048, 256, 0, stream>>>(X, Xb, 4096 * 1024);
    transpose_cast_k<<<dim3(32, 32), 256, 0, stream>>>(Wq, WqT, 1024, 1024);
    transpose_cast_k<<<dim3(8, 32), 256, 0, stream>>>(Wk, WkT, 1024, 256);
    transpose_cast_k<<<dim3(8, 32), 256, 0, stream>>>(Wv, WvT, 1024, 256);
    transpose_cast_k<<<dim3(32, 32), 256, 0, stream>>>(Wo, WoT, 1024, 1024);

    qkv_gemm<<<dim3(64, 24), 256, 0, stream>>>(Xb, WqT, WkT, WvT, bq, bk, bv, Qb, Kb, Vb);
    attn_k<<<dim3(32, 16, 2), 256, 0, stream>>>(Qb, Kb, Vb, mask, Ab);
    oproj_gemm<<<dim3(64, 16), 256, 0, stream>>>(Ab, WoT, bo, out);
}

// Round 3
// 240.230 us; speedup vs baseline: 1.3353x; 1.3353x over previous
//
#include <hip/hip_runtime.h>

typedef __bf16 bf16;
typedef __attribute__((ext_vector_type(8))) __bf16 bf16x8;
typedef __attribute__((ext_vector_type(4))) __bf16 bf16x4;
typedef __attribute__((ext_vector_type(4))) float f32x4;

#define LOG2E 1.44269504088896340736f

// ---------------- Kernel A: fp32 -> bf16 cast ----------------
__global__ __launch_bounds__(256) void cast_k(const float* __restrict__ in,
                                              bf16* __restrict__ out, int n) {
    int idx = (blockIdx.x * 256 + threadIdx.x) * 8;
    if (idx + 8 <= n) {
        float4 a = *(const float4*)(in + idx);
        float4 b = *(const float4*)(in + idx + 4);
        bf16 v[8] = {(bf16)a.x, (bf16)a.y, (bf16)a.z, (bf16)a.w,
                     (bf16)b.x, (bf16)b.y, (bf16)b.z, (bf16)b.w};
        *(uint4*)(out + idx) = *(const uint4*)v;
    }
}

// ---------------- Kernel 0: tiled transpose + cast  out[C][R] = (bf16)in[R][C] ----------------
__global__ __launch_bounds__(256) void transpose_cast_k(const float* __restrict__ in,
                                                        bf16* __restrict__ out,
                                                        int R, int C) {
    __shared__ float t[32][33];
    int tx = threadIdx.x & 31, ty = threadIdx.x >> 5;  // 32 x 8
    int rbase = blockIdx.y * 32, cbase = blockIdx.x * 32;
#pragma unroll
    for (int i = 0; i < 4; i++) {
        int r = ty + i * 8;
        t[r][tx] = in[(size_t)(rbase + r) * C + cbase + tx];
    }
    __syncthreads();
#pragma unroll
    for (int i = 0; i < 4; i++) {
        int r = ty + i * 8;
        out[(size_t)(cbase + r) * R + rbase + tx] = (bf16)t[tx][r];
    }
}

// ---------------- Kernel 0b: bf16 transpose per (b,kv): [2048][64] -> [64][2048] ----------------
__global__ __launch_bounds__(256) void vtrans_k(const unsigned short* __restrict__ in,
                                                unsigned short* __restrict__ out) {
    __shared__ unsigned short t[32][33];
    int z = blockIdx.z;
    const unsigned short* ip = in + (size_t)z * 2048 * 64;
    unsigned short* op = out + (size_t)z * 2048 * 64;
    int tx = threadIdx.x & 31, ty = threadIdx.x >> 5;
    int rbase = blockIdx.y * 32, cbase = blockIdx.x * 32;  // rows = s, cols = d
#pragma unroll
    for (int i = 0; i < 4; i++) {
        int r = ty + i * 8;
        t[r][tx] = ip[(size_t)(rbase + r) * 64 + cbase + tx];
    }
    __syncthreads();
#pragma unroll
    for (int i = 0; i < 4; i++) {
        int r = ty + i * 8;
        op[(size_t)(cbase + r) * 2048 + rbase + tx] = t[tx][r];
    }
}

// ---------------- Kernel 1: fused QKV GEMM + bias + RoPE ----------------
__global__ __launch_bounds__(256) void qkv_gemm(const bf16* __restrict__ X,
                                                const bf16* __restrict__ WqT,
                                                const bf16* __restrict__ WkT,
                                                const bf16* __restrict__ WvT,
                                                const float* __restrict__ bq,
                                                const float* __restrict__ bk,
                                                const float* __restrict__ bv,
                                                bf16* __restrict__ Qb,
                                                bf16* __restrict__ Kb,
                                                bf16* __restrict__ Vb) {
    int tt = blockIdx.x;
    int gy = blockIdx.y;
    const bf16* WT;
    const float* bias;
    bf16* dst;
    int mode, head;
    if (gy < 16)      { head = gy;      WT = WqT + (size_t)head * 64 * 1024; bias = bq + head * 64; dst = Qb; mode = 0; }
    else if (gy < 20) { head = gy - 16; WT = WkT + (size_t)head * 64 * 1024; bias = bk + head * 64; dst = Kb; mode = 1; }
    else              { head = gy - 20; WT = WvT + (size_t)head * 64 * 1024; bias = bv + head * 64; dst = Vb; mode = 2; }

    __shared__ unsigned short Xs[64 * 72];
    __shared__ unsigned short Ws[64 * 72];
    int tid = threadIdx.x;
    int w = tid >> 6, lane = tid & 63, l15 = lane & 15, quad = lane >> 4;

    f32x4 acc[4] = {};
    for (int k0 = 0; k0 < 1024; k0 += 64) {
#pragma unroll
        for (int i = tid; i < 512; i += 256) {
            int row = i >> 3, ch = i & 7;
            uint4 xv = *(const uint4*)(X + (size_t)(tt * 64 + row) * 1024 + k0 + ch * 8);
            *(uint4*)&Xs[row * 72 + ch * 8] = xv;
            uint4 wv = *(const uint4*)(WT + (size_t)row * 1024 + k0 + ch * 8);
            *(uint4*)&Ws[row * 72 + ch * 8] = wv;
        }
        __syncthreads();
        bf16x8 a0 = *(const bf16x8*)&Xs[(w * 16 + l15) * 72 + quad * 8];
        bf16x8 a1 = *(const bf16x8*)&Xs[(w * 16 + l15) * 72 + 32 + quad * 8];
#pragma unroll
        for (int c = 0; c < 4; c++) {
            bf16x8 b0 = *(const bf16x8*)&Ws[(c * 16 + l15) * 72 + quad * 8];
            bf16x8 b1 = *(const bf16x8*)&Ws[(c * 16 + l15) * 72 + 32 + quad * 8];
            acc[c] = __builtin_amdgcn_mfma_f32_16x16x32_bf16(a0, b0, acc[c], 0, 0, 0);
            acc[c] = __builtin_amdgcn_mfma_f32_16x16x32_bf16(a1, b1, acc[c], 0, 0, 0);
        }
        __syncthreads();
    }

#pragma unroll
    for (int r = 0; r < 4; r++) {
        int token = tt * 64 + w * 16 + quad * 4 + r;
        int b = token >> 11, s = token & 2047;
        float vals[4];
#pragma unroll
        for (int c = 0; c < 4; c++) vals[c] = acc[c][r] + bias[c * 16 + l15];
        if (mode <= 1) {  // RoPE for Q,K
#pragma unroll
            for (int c = 0; c < 2; c++) {
                int i = c * 16 + l15;  // 0..31
                float inv = exp2f(-0.41524100370589830f * (float)i);  // 10000^(-i/32)
                float ang = (float)s * inv;
                float sn = sinf(ang), cs = cosf(ang);
                float x1 = vals[c], x2 = vals[c + 2];
                vals[c]     = x1 * cs - x2 * sn;
                vals[c + 2] = x1 * sn + x2 * cs;
            }
        }
        size_t base;
        if (mode == 0) base = (((size_t)b * 16 + head) * 2048 + s) * 64;
        else           base = (((size_t)b * 4  + head) * 2048 + s) * 64;
#pragma unroll
        for (int c = 0; c < 4; c++) dst[base + c * 16 + l15] = (bf16)vals[c];
    }
}

// ---------------- Kernel 2: flash attention (S^T scheme) ----------------
// grid (32 qtiles, 16 heads, 2 batch), block 256 = 4 waves x 16 q-rows
// Computes S^T = K·Q^T so each lane owns ONE q (=l15): softmax = in-lane tree + 2 shfl.
// V^T pre-staged in global (VbT [bkv][64][2048]) -> vector LDS staging, no u16 scatter.
__global__ __launch_bounds__(256) void attn_k(const bf16* __restrict__ Qb,
                                              const bf16* __restrict__ Kb,
                                              const bf16* __restrict__ VbT,
                                              const float* __restrict__ mask,
                                              bf16* __restrict__ Ob) {
    int qt = blockIdx.x, h = blockIdx.y, b = blockIdx.z;
    int kvh = h >> 2;  // rep = 4

    __shared__ unsigned short Ks[64 * 72];     // [key][d]
    __shared__ unsigned short Vs[64 * 72];     // [d][key] (from VbT)
    __shared__ unsigned short Ps[4][16 * 72];  // per-wave P [q][key]
    __shared__ float Ms[64];                   // per-key bias (log2 domain)

    int tid = threadIdx.x, w = tid >> 6, lane = tid & 63, l15 = lane & 15, quad = lane >> 4;

    // Q fragment (B-operand): lane n=l15 -> q, k=quad*8+j -> d
    size_t qbase = (((size_t)b * 16 + h) * 2048 + (size_t)qt * 64 + w * 16 + l15) * 64;
    bf16x8 qa0 = *(const bf16x8*)(Qb + qbase + quad * 8);
    bf16x8 qa1 = *(const bf16x8*)(Qb + qbase + 32 + quad * 8);

    f32x4 oacc[4] = {};
    float m2 = -1e30f, lsum = 0.f;  // per-lane state for q = l15
    const float SCALE = 0.125f * LOG2E;

    size_t kRow = ((size_t)b * 4 + kvh) * 2048;  // row base in Kb
    size_t vRow = ((size_t)b * 4 + kvh) * 64;    // row base in VbT

    for (int kt = 0; kt < 32; kt++) {
#pragma unroll
        for (int it = 0; it < 2; it++) {
            int i = tid + it * 256;
            int row = i >> 3, cg = i & 7;
            uint4 kv4 = *(const uint4*)(Kb + (kRow + kt * 64 + row) * 64 + cg * 8);
            *(uint4*)&Ks[row * 72 + cg * 8] = kv4;
            uint4 vv4 = *(const uint4*)(VbT + (vRow + row) * 2048 + kt * 64 + cg * 8);
            *(uint4*)&Vs[row * 72 + cg * 8] = vv4;
        }
        if (tid < 64) {
            float mv = mask[(size_t)b * 2048 + kt * 64 + tid];
            Ms[tid] = (1.0f - mv) * (-1e9f) * LOG2E;
        }
        __syncthreads();

        // ---- S^T = K·Q^T : A = K rows (m=key), B = Q (n=q) ----
        f32x4 sc[4];
#pragma unroll
        for (int c = 0; c < 4; c++) {
            bf16x8 ka0 = *(const bf16x8*)&Ks[(c * 16 + l15) * 72 + quad * 8];
            bf16x8 ka1 = *(const bf16x8*)&Ks[(c * 16 + l15) * 72 + 32 + quad * 8];
            f32x4 z = {};
            z = __builtin_amdgcn_mfma_f32_16x16x32_bf16(ka0, qa0, z, 0, 0, 0);
            z = __builtin_amdgcn_mfma_f32_16x16x32_bf16(ka1, qa1, z, 0, 0, 0);
            // element (c,r): key = c*16+quad*4+r, q = l15
            f32x4 bias4 = *(const f32x4*)&Ms[c * 16 + quad * 4];
#pragma unroll
            for (int r = 0; r < 4; r++) sc[c][r] = z[r] * SCALE + bias4[r];
        }

        // ---- online softmax over keys (per-lane q = l15) ----
        f32x4 m4 = sc[0];
#pragma unroll
        for (int c = 1; c < 4; c++)
#pragma unroll
            for (int r = 0; r < 4; r++) m4[r] = fmaxf(m4[r], sc[c][r]);
        float mx = fmaxf(fmaxf(m4[0], m4[1]), fmaxf(m4[2], m4[3]));
        mx = fmaxf(mx, __shfl_xor(mx, 16, 64));
        mx = fmaxf(mx, __shfl_xor(mx, 32, 64));
        float mn = fmaxf(m2, mx);
        float alpha = exp2f(m2 - mn);
        m2 = mn;
        float rs = 0.f;
#pragma unroll
        for (int c = 0; c < 4; c++)
#pragma unroll
            for (int r = 0; r < 4; r++) { sc[c][r] = exp2f(sc[c][r] - mn); rs += sc[c][r]; }
        rs += __shfl_xor(rs, 16, 64);
        rs += __shfl_xor(rs, 32, 64);
        lsum = lsum * alpha + rs;

        // ---- pack P (4 consecutive keys per (c,quad)) -> per-wave LDS, b64 writes ----
#pragma unroll
        for (int c = 0; c < 4; c++) {
            bf16x4 pv = {(bf16)sc[c][0], (bf16)sc[c][1], (bf16)sc[c][2], (bf16)sc[c][3]};
            *(bf16x4*)&Ps[w][l15 * 72 + c * 16 + quad * 4] = pv;
        }

        // ---- rescale O accumulator (rows are q = quad*4+r) ----
        float alpha_r[4];
#pragma unroll
        for (int r = 0; r < 4; r++) alpha_r[r] = __shfl(alpha, quad * 4 + r, 64);
#pragma unroll
        for (int c = 0; c < 4; c++)
#pragma unroll
            for (int r = 0; r < 4; r++) oacc[c][r] *= alpha_r[r];

        // ---- O += P·V : A = P[q][key] (same wave -> lgkmcnt only, no barrier) ----
        bf16x8 pa0 = *(const bf16x8*)&Ps[w][l15 * 72 + quad * 8];
        bf16x8 pa1 = *(const bf16x8*)&Ps[w][l15 * 72 + 32 + quad * 8];
#pragma unroll
        for (int c = 0; c < 4; c++) {
            bf16x8 vb0 = *(const bf16x8*)&Vs[(c * 16 + l15) * 72 + quad * 8];
            bf16x8 vb1 = *(const bf16x8*)&Vs[(c * 16 + l15) * 72 + 32 + quad * 8];
            oacc[c] = __builtin_amdgcn_mfma_f32_16x16x32_bf16(pa0, vb0, oacc[c], 0, 0, 0);
            oacc[c] = __builtin_amdgcn_mfma_f32_16x16x32_bf16(pa1, vb1, oacc[c], 0, 0, 0);
        }
        __syncthreads();  // Ks/Vs reads done before next staging overwrites
    }

    // epilogue: O[b][q][h*64+d] = oacc / lsum(q)
    float linv[4];
#pragma unroll
    for (int r = 0; r < 4; r++) linv[r] = 1.0f / __shfl(lsum, quad * 4 + r, 64);
#pragma unroll
    for (int r = 0; r < 4; r++) {
        int q = qt * 64 + w * 16 + quad * 4 + r;
        size_t base = ((size_t)b * 2048 + q) * 1024 + h * 64;
#pragma unroll
        for (int c = 0; c < 4; c++) Ob[base + c * 16 + l15] = (bf16)(oacc[c][r] * linv[r]);
    }
}

// ---------------- Kernel 3: O projection (fp32 output) ----------------
__global__ __launch_bounds__(256) void oproj_gemm(const bf16* __restrict__ A,
                                                  const bf16* __restrict__ WoT,
                                                  const float* __restrict__ bo,
                                                  float* __restrict__ out) {
    int tt = blockIdx.x, gy = blockIdx.y;
    const bf16* WT = WoT + (size_t)gy * 64 * 1024;

    __shared__ unsigned short Xs[64 * 72];
    __shared__ unsigned short Ws[64 * 72];
    int tid = threadIdx.x;
    int w = tid >> 6, lane = tid & 63, l15 = lane & 15, quad = lane >> 4;

    f32x4 acc[4] = {};
    for (int k0 = 0; k0 < 1024; k0 += 64) {
#pragma unroll
        for (int i = tid; i < 512; i += 256) {
            int row = i >> 3, ch = i & 7;
            uint4 xv = *(const uint4*)(A + (size_t)(tt * 64 + row) * 1024 + k0 + ch * 8);
            *(uint4*)&Xs[row * 72 + ch * 8] = xv;
            uint4 wv = *(const uint4*)(WT + (size_t)row * 1024 + k0 + ch * 8);
            *(uint4*)&Ws[row * 72 + ch * 8] = wv;
        }
        __syncthreads();
        bf16x8 a0 = *(const bf16x8*)&Xs[(w * 16 + l15) * 72 + quad * 8];
        bf16x8 a1 = *(const bf16x8*)&Xs[(w * 16 + l15) * 72 + 32 + quad * 8];
#pragma unroll
        for (int c = 0; c < 4; c++) {
            bf16x8 b0 = *(const bf16x8*)&Ws[(c * 16 + l15) * 72 + quad * 8];
            bf16x8 b1 = *(const bf16x8*)&Ws[(c * 16 + l15) * 72 + 32 + quad * 8];
            acc[c] = __builtin_amdgcn_mfma_f32_16x16x32_bf16(a0, b0, acc[c], 0, 0, 0);
            acc[c] = __builtin_amdgcn_mfma_f32_16x16x32_bf16(a1, b1, acc[c], 0, 0, 0);
        }
        __syncthreads();
    }
#pragma unroll
    for (int r = 0; r < 4; r++) {
        int token = tt * 64 + w * 16 + quad * 4 + r;
#pragma unroll
        for (int c = 0; c < 4; c++) {
            int n = gy * 64 + c * 16 + l15;
            out[(size_t)token * 1024 + n] = acc[c][r] + bo[n];
        }
    }
}

// ---------------- launch ----------------
extern "C" void kernel_launch(void* const* d_in, const int* in_sizes, int n_in,
                              void* d_out, int out_size, void* d_ws, size_t ws_size,
                              hipStream_t stream) {
    const float* X    = (const float*)d_in[0];
    const float* mask = (const float*)d_in[1];
    const float* Wq   = (const float*)d_in[2];
    const float* bq   = (const float*)d_in[3];
    const float* Wk   = (const float*)d_in[4];
    const float* bk   = (const float*)d_in[5];
    const float* Wv   = (const float*)d_in[6];
    const float* bv   = (const float*)d_in[7];
    const float* Wo   = (const float*)d_in[8];
    const float* bo   = (const float*)d_in[9];
    float* out = (float*)d_out;
    bf16* ws  = (bf16*)d_ws;

    // workspace layout (bf16 elements)
    bf16* Xb  = ws;                       // 4096x1024 (dead after qkv_gemm -> reused for VbT)
    bf16* WqT = Xb + (size_t)4096 * 1024; // 1024x1024
    bf16* WkT = WqT + 1024 * 1024;        // 256x1024
    bf16* WvT = WkT + 256 * 1024;         // 256x1024
    bf16* WoT = WvT + 256 * 1024;         // 1024x1024
    bf16* Qb  = WoT + 1024 * 1024;        // [2][16][2048][64]
    bf16* Kb  = Qb + (size_t)2 * 16 * 2048 * 64;  // [2][4][2048][64]
    bf16* Vb  = Kb + (size_t)2 * 4 * 2048 * 64;   // [2][4][2048][64]
    bf16* Ab  = Vb + (size_t)2 * 4 * 2048 * 64;   // [2][2048][1024]
    bf16* VbT = Xb;                               // [2][4][64][2048] (1M elems, fits in Xb's 4M)

    cast_k<<<2048, 256, 0, stream>>>(X, Xb, 4096 * 1024);
    transpose_cast_k<<<dim3(32, 32), 256, 0, stream>>>(Wq, WqT, 1024, 1024);
    transpose_cast_k<<<dim3(8, 32), 256, 0, stream>>>(Wk, WkT, 1024, 256);
    transpose_cast_k<<<dim3(8, 32), 256, 0, stream>>>(Wv, WvT, 1024, 256);
    transpose_cast_k<<<dim3(32, 32), 256, 0, stream>>>(Wo, WoT, 1024, 1024);

    qkv_gemm<<<dim3(64, 24), 256, 0, stream>>>(Xb, WqT, WkT, WvT, bq, bk, bv, Qb, Kb, Vb);
    vtrans_k<<<dim3(2, 64, 8), 256, 0, stream>>>((const unsigned short*)Vb, (unsigned short*)VbT);
    attn_k<<<dim3(32, 16, 2), 256, 0, stream>>>(Qb, Kb, VbT, mask, Ab);
    oproj_gemm<<<dim3(64, 16), 256, 0, stream>>>(Ab, WoT, bo, out);
}

// Round 4
// 228.580 us; speedup vs baseline: 1.4034x; 1.0510x over previous
//
#include <hip/hip_runtime.h>

typedef __bf16 bf16;
typedef __attribute__((ext_vector_type(8))) __bf16 bf16x8;
typedef __attribute__((ext_vector_type(4))) __bf16 bf16x4;
typedef __attribute__((ext_vector_type(4))) float f32x4;

#define LOG2E 1.44269504088896340736f
#define QSCALE 0.18033688011112042f   // 0.125 * log2(e), folded into Q

// ---------------- Kernel P: fused prep ----------------
// sections: [0,2048) cast X; [2048,3072) Wq^T; [3072,3328) Wk^T; [3328,3584) Wv^T;
//           [3584,4608) Wo^T; [4608,4864) rope table
__device__ inline void tr_tile(const float* __restrict__ in, bf16* __restrict__ out,
                               int R, int C, int bx, int by, int tid) {
    __shared__ float t[32][33];
    int tx = tid & 31, ty = tid >> 5;
    int rbase = by * 32, cbase = bx * 32;
#pragma unroll
    for (int i = 0; i < 4; i++) {
        int r = ty + i * 8;
        t[r][tx] = in[(size_t)(rbase + r) * C + cbase + tx];
    }
    __syncthreads();
#pragma unroll
    for (int i = 0; i < 4; i++) {
        int r = ty + i * 8;
        out[(size_t)(cbase + r) * R + rbase + tx] = (bf16)t[tx][r];
    }
}

__global__ __launch_bounds__(256) void prep_k(const float* __restrict__ X,
                                              const float* __restrict__ Wq,
                                              const float* __restrict__ Wk,
                                              const float* __restrict__ Wv,
                                              const float* __restrict__ Wo,
                                              bf16* __restrict__ Xb,
                                              bf16* __restrict__ WqT,
                                              bf16* __restrict__ WkT,
                                              bf16* __restrict__ WvT,
                                              bf16* __restrict__ WoT,
                                              float2* __restrict__ rt) {
    int blk = blockIdx.x, tid = threadIdx.x;
    if (blk < 2048) {
        int idx = (blk * 256 + tid) * 8;
        float4 a = *(const float4*)(X + idx);
        float4 b = *(const float4*)(X + idx + 4);
        bf16 v[8] = {(bf16)a.x, (bf16)a.y, (bf16)a.z, (bf16)a.w,
                     (bf16)b.x, (bf16)b.y, (bf16)b.z, (bf16)b.w};
        *(uint4*)(Xb + idx) = *(const uint4*)v;
    } else if (blk < 3072) {
        int t = blk - 2048; tr_tile(Wq, WqT, 1024, 1024, t & 31, t >> 5, tid);
    } else if (blk < 3328) {
        int t = blk - 3072; tr_tile(Wk, WkT, 1024, 256, t & 7, t >> 3, tid);
    } else if (blk < 3584) {
        int t = blk - 3328; tr_tile(Wv, WvT, 1024, 256, t & 7, t >> 3, tid);
    } else if (blk < 4608) {
        int t = blk - 3584; tr_tile(Wo, WoT, 1024, 1024, t & 31, t >> 5, tid);
    } else {
        int idx = (blk - 4608) * 256 + tid;  // idx = s*32 + i, s<2048, i<32
        int s = idx >> 5, i = idx & 31;
        float inv = exp2f(-0.41524100370589830f * (float)i);  // 10000^(-i/32)
        float ang = (float)s * inv;
        rt[idx] = make_float2(cosf(ang), sinf(ang));
    }
}

// ---------------- Kernel 0b: bf16 transpose per (b,kv): [2048][64] -> [64][2048] ----------------
__global__ __launch_bounds__(256) void vtrans_k(const unsigned short* __restrict__ in,
                                                unsigned short* __restrict__ out) {
    __shared__ unsigned short t[32][33];
    int z = blockIdx.z;
    const unsigned short* ip = in + (size_t)z * 2048 * 64;
    unsigned short* op = out + (size_t)z * 2048 * 64;
    int tx = threadIdx.x & 31, ty = threadIdx.x >> 5;
    int rbase = blockIdx.y * 32, cbase = blockIdx.x * 32;
#pragma unroll
    for (int i = 0; i < 4; i++) {
        int r = ty + i * 8;
        t[r][tx] = ip[(size_t)(rbase + r) * 64 + cbase + tx];
    }
    __syncthreads();
#pragma unroll
    for (int i = 0; i < 4; i++) {
        int r = ty + i * 8;
        op[(size_t)(cbase + r) * 2048 + rbase + tx] = t[tx][r];
    }
}

// ---------------- Kernel 1: fused QKV GEMM + bias + RoPE (table) + Q-prescale ----------------
__global__ __launch_bounds__(256) void qkv_gemm(const bf16* __restrict__ X,
                                                const bf16* __restrict__ WqT,
                                                const bf16* __restrict__ WkT,
                                                const bf16* __restrict__ WvT,
                                                const float* __restrict__ bq,
                                                const float* __restrict__ bk,
                                                const float* __restrict__ bv,
                                                const float2* __restrict__ rt,
                                                bf16* __restrict__ Qb,
                                                bf16* __restrict__ Kb,
                                                bf16* __restrict__ Vb) {
    int tt = blockIdx.x;
    int gy = blockIdx.y;
    const bf16* WT;
    const float* bias;
    bf16* dst;
    int mode, head;
    if (gy < 16)      { head = gy;      WT = WqT + (size_t)head * 64 * 1024; bias = bq + head * 64; dst = Qb; mode = 0; }
    else if (gy < 20) { head = gy - 16; WT = WkT + (size_t)head * 64 * 1024; bias = bk + head * 64; dst = Kb; mode = 1; }
    else              { head = gy - 20; WT = WvT + (size_t)head * 64 * 1024; bias = bv + head * 64; dst = Vb; mode = 2; }

    __shared__ unsigned short Xs[64 * 72];
    __shared__ unsigned short Ws[64 * 72];
    int tid = threadIdx.x;
    int w = tid >> 6, lane = tid & 63, l15 = lane & 15, quad = lane >> 4;

    f32x4 acc[4] = {};
    for (int k0 = 0; k0 < 1024; k0 += 64) {
#pragma unroll
        for (int i = tid; i < 512; i += 256) {
            int row = i >> 3, ch = i & 7;
            uint4 xv = *(const uint4*)(X + (size_t)(tt * 64 + row) * 1024 + k0 + ch * 8);
            *(uint4*)&Xs[row * 72 + ch * 8] = xv;
            uint4 wv = *(const uint4*)(WT + (size_t)row * 1024 + k0 + ch * 8);
            *(uint4*)&Ws[row * 72 + ch * 8] = wv;
        }
        __syncthreads();
        bf16x8 a0 = *(const bf16x8*)&Xs[(w * 16 + l15) * 72 + quad * 8];
        bf16x8 a1 = *(const bf16x8*)&Xs[(w * 16 + l15) * 72 + 32 + quad * 8];
#pragma unroll
        for (int c = 0; c < 4; c++) {
            bf16x8 b0 = *(const bf16x8*)&Ws[(c * 16 + l15) * 72 + quad * 8];
            bf16x8 b1 = *(const bf16x8*)&Ws[(c * 16 + l15) * 72 + 32 + quad * 8];
            acc[c] = __builtin_amdgcn_mfma_f32_16x16x32_bf16(a0, b0, acc[c], 0, 0, 0);
            acc[c] = __builtin_amdgcn_mfma_f32_16x16x32_bf16(a1, b1, acc[c], 0, 0, 0);
        }
        __syncthreads();
    }

#pragma unroll
    for (int r = 0; r < 4; r++) {
        int token = tt * 64 + w * 16 + quad * 4 + r;
        int b = token >> 11, s = token & 2047;
        float vals[4];
#pragma unroll
        for (int c = 0; c < 4; c++) vals[c] = acc[c][r] + bias[c * 16 + l15];
        if (mode <= 1) {  // RoPE for Q,K via table
#pragma unroll
            for (int c = 0; c < 2; c++) {
                float2 cs2 = rt[s * 32 + c * 16 + l15];
                float x1 = vals[c], x2 = vals[c + 2];
                vals[c]     = x1 * cs2.x - x2 * cs2.y;
                vals[c + 2] = x1 * cs2.y + x2 * cs2.x;
            }
        }
        if (mode == 0) {  // fold softmax scale (log2 domain) into Q
#pragma unroll
            for (int c = 0; c < 4; c++) vals[c] *= QSCALE;
        }
        size_t base;
        if (mode == 0) base = (((size_t)b * 16 + head) * 2048 + s) * 64;
        else           base = (((size_t)b * 4  + head) * 2048 + s) * 64;
#pragma unroll
        for (int c = 0; c < 4; c++) dst[base + c * 16 + l15] = (bf16)vals[c];
    }
}

// ---------------- Kernel 2: flash attention (S^T scheme) ----------------
// grid (32 qtiles, 16 heads, 2 batch), block 256 = 4 waves x 16 q-rows
__global__ __launch_bounds__(256) void attn_k(const bf16* __restrict__ Qb,
                                              const bf16* __restrict__ Kb,
                                              const bf16* __restrict__ VbT,
                                              const float* __restrict__ mask,
                                              bf16* __restrict__ Ob) {
    int qt = blockIdx.x, h = blockIdx.y, b = blockIdx.z;
    int kvh = h >> 2;  // rep = 4

    __shared__ unsigned short Ks[64 * 72];     // [key][d]
    __shared__ unsigned short Vs[64 * 72];     // [d][key] (from VbT)
    __shared__ unsigned short Ps[4][16 * 72];  // per-wave P [q][key]
    __shared__ float Ms[64];                   // per-key bias (log2 domain)
    __shared__ int mflag;

    int tid = threadIdx.x, w = tid >> 6, lane = tid & 63, l15 = lane & 15, quad = lane >> 4;

    // ---- mask-all-ones block flag (mask row is constant for this block) ----
    if (tid == 0) mflag = 1;
    __syncthreads();
    {
        float4 m0 = *(const float4*)(mask + (size_t)b * 2048 + tid * 8);
        float4 m1 = *(const float4*)(mask + (size_t)b * 2048 + tid * 8 + 4);
        bool ones = (m0.x == 1.f && m0.y == 1.f && m0.z == 1.f && m0.w == 1.f &&
                     m1.x == 1.f && m1.y == 1.f && m1.z == 1.f && m1.w == 1.f);
        if (!ones) mflag = 0;
    }
    __syncthreads();
    const bool maskOnes = (mflag != 0);

    // Q fragment (B-operand): lane n=l15 -> q, k=quad*8+j -> d. Q already scaled by QSCALE.
    size_t qbase = (((size_t)b * 16 + h) * 2048 + (size_t)qt * 64 + w * 16 + l15) * 64;
    bf16x8 qa0 = *(const bf16x8*)(Qb + qbase + quad * 8);
    bf16x8 qa1 = *(const bf16x8*)(Qb + qbase + 32 + quad * 8);

    f32x4 oacc[4] = {};
    float m2 = -1e30f, lsum = 0.f;  // per-lane state for q = l15

    size_t kRow = ((size_t)b * 4 + kvh) * 2048;  // row base in Kb
    size_t vRow = ((size_t)b * 4 + kvh) * 64;    // row base in VbT

    for (int kt = 0; kt < 32; kt++) {
#pragma unroll
        for (int it = 0; it < 2; it++) {
            int i = tid + it * 256;
            int row = i >> 3, cg = i & 7;
            uint4 kv4 = *(const uint4*)(Kb + (kRow + kt * 64 + row) * 64 + cg * 8);
            *(uint4*)&Ks[row * 72 + cg * 8] = kv4;
            uint4 vv4 = *(const uint4*)(VbT + (vRow + row) * 2048 + kt * 64 + cg * 8);
            *(uint4*)&Vs[row * 72 + cg * 8] = vv4;
        }
        if (!maskOnes && tid < 64) {
            float mv = mask[(size_t)b * 2048 + kt * 64 + tid];
            Ms[tid] = (1.0f - mv) * (-1e9f) * LOG2E;
        }
        __syncthreads();

        // ---- S^T = K·Q^T (already in log2 domain via Q prescale) ----
        f32x4 sc[4];
#pragma unroll
        for (int c = 0; c < 4; c++) {
            bf16x8 ka0 = *(const bf16x8*)&Ks[(c * 16 + l15) * 72 + quad * 8];
            bf16x8 ka1 = *(const bf16x8*)&Ks[(c * 16 + l15) * 72 + 32 + quad * 8];
            f32x4 z = {};
            z = __builtin_amdgcn_mfma_f32_16x16x32_bf16(ka0, qa0, z, 0, 0, 0);
            z = __builtin_amdgcn_mfma_f32_16x16x32_bf16(ka1, qa1, z, 0, 0, 0);
            sc[c] = z;  // element (c,r): key = c*16+quad*4+r, q = l15
        }
        if (!maskOnes) {
#pragma unroll
            for (int c = 0; c < 4; c++) {
                f32x4 bias4 = *(const f32x4*)&Ms[c * 16 + quad * 4];
#pragma unroll
                for (int r = 0; r < 4; r++) sc[c][r] += bias4[r];
            }
        }

        // ---- online softmax over keys (per-lane q = l15) ----
        f32x4 m4 = sc[0];
#pragma unroll
        for (int c = 1; c < 4; c++)
#pragma unroll
            for (int r = 0; r < 4; r++) m4[r] = fmaxf(m4[r], sc[c][r]);
        float mx = fmaxf(fmaxf(m4[0], m4[1]), fmaxf(m4[2], m4[3]));
        mx = fmaxf(mx, __shfl_xor(mx, 16, 64));
        mx = fmaxf(mx, __shfl_xor(mx, 32, 64));

        if (__any(mx > m2)) {  // running max increased for some q in this wave
            float mn = fmaxf(m2, mx);
            float alpha = exp2f(m2 - mn);
            m2 = mn;
            lsum *= alpha;
            float alpha_r[4];
#pragma unroll
            for (int r = 0; r < 4; r++) alpha_r[r] = __shfl(alpha, quad * 4 + r, 64);
#pragma unroll
            for (int c = 0; c < 4; c++)
#pragma unroll
                for (int r = 0; r < 4; r++) oacc[c][r] *= alpha_r[r];
        }

        float rs = 0.f;
#pragma unroll
        for (int c = 0; c < 4; c++)
#pragma unroll
            for (int r = 0; r < 4; r++) { sc[c][r] = exp2f(sc[c][r] - m2); rs += sc[c][r]; }
        rs += __shfl_xor(rs, 16, 64);
        rs += __shfl_xor(rs, 32, 64);
        lsum += rs;

        // ---- pack P (4 consecutive keys per (c,quad)) -> per-wave LDS, b64 writes ----
#pragma unroll
        for (int c = 0; c < 4; c++) {
            bf16x4 pv = {(bf16)sc[c][0], (bf16)sc[c][1], (bf16)sc[c][2], (bf16)sc[c][3]};
            *(bf16x4*)&Ps[w][l15 * 72 + c * 16 + quad * 4] = pv;
        }

        // ---- O += P·V : A = P[q][key] (same wave -> lgkmcnt only, no barrier) ----
        bf16x8 pa0 = *(const bf16x8*)&Ps[w][l15 * 72 + quad * 8];
        bf16x8 pa1 = *(const bf16x8*)&Ps[w][l15 * 72 + 32 + quad * 8];
#pragma unroll
        for (int c = 0; c < 4; c++) {
            bf16x8 vb0 = *(const bf16x8*)&Vs[(c * 16 + l15) * 72 + quad * 8];
            bf16x8 vb1 = *(const bf16x8*)&Vs[(c * 16 + l15) * 72 + 32 + quad * 8];
            oacc[c] = __builtin_amdgcn_mfma_f32_16x16x32_bf16(pa0, vb0, oacc[c], 0, 0, 0);
            oacc[c] = __builtin_amdgcn_mfma_f32_16x16x32_bf16(pa1, vb1, oacc[c], 0, 0, 0);
        }
        __syncthreads();  // Ks/Vs reads done before next staging overwrites
    }

    // epilogue: O[b][q][h*64+d] = oacc / lsum(q)
    float linv[4];
#pragma unroll
    for (int r = 0; r < 4; r++) linv[r] = 1.0f / __shfl(lsum, quad * 4 + r, 64);
#pragma unroll
    for (int r = 0; r < 4; r++) {
        int q = qt * 64 + w * 16 + quad * 4 + r;
        size_t base = ((size_t)b * 2048 + q) * 1024 + h * 64;
#pragma unroll
        for (int c = 0; c < 4; c++) Ob[base + c * 16 + l15] = (bf16)(oacc[c][r] * linv[r]);
    }
}

// ---------------- Kernel 3: O projection (fp32 output) ----------------
__global__ __launch_bounds__(256) void oproj_gemm(const bf16* __restrict__ A,
                                                  const bf16* __restrict__ WoT,
                                                  const float* __restrict__ bo,
                                                  float* __restrict__ out) {
    int tt = blockIdx.x, gy = blockIdx.y;
    const bf16* WT = WoT + (size_t)gy * 64 * 1024;

    __shared__ unsigned short Xs[64 * 72];
    __shared__ unsigned short Ws[64 * 72];
    int tid = threadIdx.x;
    int w = tid >> 6, lane = tid & 63, l15 = lane & 15, quad = lane >> 4;

    f32x4 acc[4] = {};
    for (int k0 = 0; k0 < 1024; k0 += 64) {
#pragma unroll
        for (int i = tid; i < 512; i += 256) {
            int row = i >> 3, ch = i & 7;
            uint4 xv = *(const uint4*)(A + (size_t)(tt * 64 + row) * 1024 + k0 + ch * 8);
            *(uint4*)&Xs[row * 72 + ch * 8] = xv;
            uint4 wv = *(const uint4*)(WT + (size_t)row * 1024 + k0 + ch * 8);
            *(uint4*)&Ws[row * 72 + ch * 8] = wv;
        }
        __syncthreads();
        bf16x8 a0 = *(const bf16x8*)&Xs[(w * 16 + l15) * 72 + quad * 8];
        bf16x8 a1 = *(const bf16x8*)&Xs[(w * 16 + l15) * 72 + 32 + quad * 8];
#pragma unroll
        for (int c = 0; c < 4; c++) {
            bf16x8 b0 = *(const bf16x8*)&Ws[(c * 16 + l15) * 72 + quad * 8];
            bf16x8 b1 = *(const bf16x8*)&Ws[(c * 16 + l15) * 72 + 32 + quad * 8];
            acc[c] = __builtin_amdgcn_mfma_f32_16x16x32_bf16(a0, b0, acc[c], 0, 0, 0);
            acc[c] = __builtin_amdgcn_mfma_f32_16x16x32_bf16(a1, b1, acc[c], 0, 0, 0);
        }
        __syncthreads();
    }
#pragma unroll
    for (int r = 0; r < 4; r++) {
        int token = tt * 64 + w * 16 + quad * 4 + r;
#pragma unroll
        for (int c = 0; c < 4; c++) {
            int n = gy * 64 + c * 16 + l15;
            out[(size_t)token * 1024 + n] = acc[c][r] + bo[n];
        }
    }
}

// ---------------- launch ----------------
extern "C" void kernel_launch(void* const* d_in, const int* in_sizes, int n_in,
                              void* d_out, int out_size, void* d_ws, size_t ws_size,
                              hipStream_t stream) {
    const float* X    = (const float*)d_in[0];
    const float* mask = (const float*)d_in[1];
    const float* Wq   = (const float*)d_in[2];
    const float* bq   = (const float*)d_in[3];
    const float* Wk   = (const float*)d_in[4];
    const float* bk   = (const float*)d_in[5];
    const float* Wv   = (const float*)d_in[6];
    const float* bv   = (const float*)d_in[7];
    const float* Wo   = (const float*)d_in[8];
    const float* bo   = (const float*)d_in[9];
    float* out = (float*)d_out;
    bf16* ws  = (bf16*)d_ws;

    // workspace layout (bf16 elements)
    bf16* Xb  = ws;                       // 4096x1024 (dead after qkv_gemm -> reused for VbT)
    bf16* WqT = Xb + (size_t)4096 * 1024; // 1024x1024
    bf16* WkT = WqT + 1024 * 1024;        // 256x1024
    bf16* WvT = WkT + 256 * 1024;         // 256x1024
    bf16* WoT = WvT + 256 * 1024;         // 1024x1024
    bf16* Qb  = WoT + 1024 * 1024;        // [2][16][2048][64]
    bf16* Kb  = Qb + (size_t)2 * 16 * 2048 * 64;  // [2][4][2048][64]
    bf16* Vb  = Kb + (size_t)2 * 4 * 2048 * 64;   // [2][4][2048][64]
    bf16* Ab  = Vb + (size_t)2 * 4 * 2048 * 64;   // [2][2048][1024]
    float2* rt = (float2*)(Ab + (size_t)2 * 2048 * 1024);  // [2048][32] cos/sin
    bf16* VbT = Xb;                               // [2][4][64][2048]

    prep_k<<<4864, 256, 0, stream>>>(X, Wq, Wk, Wv, Wo, Xb, WqT, WkT, WvT, WoT, rt);
    qkv_gemm<<<dim3(64, 24), 256, 0, stream>>>(Xb, WqT, WkT, WvT, bq, bk, bv, rt, Qb, Kb, Vb);
    vtrans_k<<<dim3(2, 64, 8), 256, 0, stream>>>((const unsigned short*)Vb, (unsigned short*)VbT);
    attn_k<<<dim3(32, 16, 2), 256, 0, stream>>>(Qb, Kb, VbT, mask, Ab);
    oproj_gemm<<<dim3(64, 16), 256, 0, stream>>>(Ab, WoT, bo, out);
}